// Round 21
// baseline (77.252 us; speedup 1.0000x reference)
//
#include <hip/hip_runtime.h>
#include <hip/hip_bf16.h>

#define BATCH 65536
#define INF   64
#define OUTF  256
#define NMAT  15
#define RPB   256          // rows per block
#define LDSW  36           // 32 cols + 4 pad floats

typedef __bf16 bf16x8 __attribute__((ext_vector_type(8)));
typedef float  f32x4  __attribute__((ext_vector_type(4)));

__device__ __forceinline__ unsigned short f2bf(float f) {
    unsigned int u = __float_as_uint(f);
    unsigned int r = (u + 0x7FFFu + ((u >> 16) & 1u)) >> 16;
    return (unsigned short)r;
}

// Opaque weight load: asm-produced value cannot be rematerialized/sunk by the
// compiler (R15/R17/R18 failure mode structurally impossible).
__device__ __forceinline__ void wload(bf16x8& d, const void* p) {
    asm volatile("global_load_dwordx4 %0, %1, off" : "=v"(d) : "v"(p));
}

// ---------------------------------------------------------------------------
// Weight layout (swizzled): per (mat w, 16-col strip cs):
//   byte = ((w*16+cs)*2+s)*1024 + lane*16   (lane = g*16+l15; k = s*32+g*8+j)
// slot order: 0=d1t, 1=d1_0, 2=M0, 3=d1_1, 4=M1, 5=M2, 6=d1_2, 7=M3, 8=M4,
// 9=M5, 10=d1_3, 11=M6, 12=M7, 13=M8, 14=M9  (M_p = dn_w2[p]*dn_w1[p][None,:])
// ---------------------------------------------------------------------------
__global__ void build_weights(const float* __restrict__ d1t_w,
                              const float* __restrict__ d1_w,
                              const float* __restrict__ dn_w1,
                              const float* __restrict__ dn_w2,
                              unsigned short* __restrict__ wcs) {
    const int idx = blockIdx.x * 256 + threadIdx.x;   // one 16-B chunk
    if (idx >= NMAT * OUTF * INF / 8) return;
    const signed char kind[NMAT] = {0,1,2,1,2,2,1,2,2,2,1,2,2,2,2};
    const signed char sidx[NMAT] = {0,0,0,1,1,2,2,3,4,5,3,6,7,8,9};
    const int slot = idx >> 11, rem8 = idx & 2047;
    const int o = rem8 >> 3, cc = rem8 & 7;
    const int s = cc >> 2, g = cc & 3;
    const int i0 = cc * 8;
    const int cs = o >> 4, l = o & 15;
    const int k = kind[slot], si = sidx[slot];
    unsigned short o8[8];
#pragma unroll
    for (int j = 0; j < 8; ++j) {
        const int e = o * INF + i0 + j;
        float v;
        if (k == 0)      v = d1t_w[e];
        else if (k == 1) v = d1_w[si * OUTF * INF + e];
        else             v = dn_w2[si * OUTF * INF + e] * dn_w1[si * INF + i0 + j];
        o8[j] = f2bf(v);
    }
    char* dst = (char*)wcs + (((size_t)slot * 16 + cs) * 2 + s) * 1024 + g * 256 + l * 16;
    *(bf16x8*)dst = *(bf16x8*)o8;
}

// R20 structure with DIRECT fp32 x (no prep pass) + asm-pinned weights.
// Role A: 7 mats, role B: 8; partials combine in LDS; NT full-128B-line stores.
__global__ __launch_bounds__(256, 3) void taylor_kernel(
    const float* __restrict__ x, const float* __restrict__ d0w,
    const unsigned short* __restrict__ wcs, float* __restrict__ out)
{
    __shared__ float sbuf[2][2][32 * LDSW];   // 18 KB

    const int lane  = threadIdx.x & 63;
    const int wv    = threadIdx.x >> 6;   // 0..3
    const int strip = wv >> 1;            // 0..1
    const int role  = wv & 1;             // 0=A, 1=B
    const int l15   = lane & 15;
    const int g     = lane >> 4;
    // sharers of one row-chunk: bids {rc + 256k} -> all == rc mod 8 -> same XCD
    const int cg    = blockIdx.x >> 8;    // 32-col group (0..7)
    const int rc    = blockIdx.x & 255;   // row-chunk (256 rows)
    const int cs    = cg * 2 + strip;     // global 16-col strip id (0..15)

    // ---- weight prologue: opaque asm loads (residency-guaranteed) ----------
    const int MA[8] = {0, 1, 2, 6, 7, 8, 9, 9};       // A uses first 7
    const int MB[8] = {3, 4, 5, 10, 11, 12, 13, 14};  // B uses all 8
    bf16x8 b[8][2];
    const char* wb0 = (const char*)wcs + lane * 16;
#pragma unroll
    for (int i = 0; i < 8; ++i) {
        const int m = role ? MB[i] : MA[i];
        if (role == 0 && i == 7) continue;            // A: only 7 mats
        const char* wp = wb0 + (((size_t)m * 16 + cs) * 2) * 1024;
        wload(b[i][0], wp);
        wload(b[i][1], wp + 1024);
    }
    asm volatile("s_waitcnt vmcnt(0)" ::: "memory");
    __builtin_amdgcn_sched_barrier(0);

    const f32x4 d0v = *(const f32x4*)(d0w + cs * 16 + g * 4);
    const size_t row0 = (size_t)rc * RPB;

#pragma unroll
    for (int t = 0; t < 8; ++t) {
        // ---- fp32 x tile -> bf16 frags in-register -------------------------
        bf16x8 u00, u01, u10, u11;
        {
            const float* xp0 = x + (row0 + (size_t)t * 32 + l15) * INF + g * 8;
            const float* xp1 = xp0 + 16 * INF;
            f32x4 v0, v1; bf16x8 fr;
#define CVT8(dst, p0) { v0 = *(const f32x4*)(p0); v1 = *(const f32x4*)((p0) + 4); \
            _Pragma("unroll") \
            for (int j = 0; j < 4; ++j) { fr[j] = (__bf16)v0[j]; fr[4+j] = (__bf16)v1[j]; } dst = fr; }
            CVT8(u00, xp0); CVT8(u01, xp0 + 32); CVT8(u10, xp1); CVT8(u11, xp1 + 32);
#undef CVT8
        }

        f32x4 res0, res1, tmp0, tmp1, y0, y1;
        const f32x4 z = {0.f, 0.f, 0.f, 0.f};
        __builtin_amdgcn_s_setprio(1);
#define Y4(bi, c0)                                                                  \
        y0 = __builtin_amdgcn_mfma_f32_16x16x32_bf16(b[bi][0], u00, c0, 0, 0, 0);   \
        y1 = __builtin_amdgcn_mfma_f32_16x16x32_bf16(b[bi][0], u10, c0, 0, 0, 0);   \
        y0 = __builtin_amdgcn_mfma_f32_16x16x32_bf16(b[bi][1], u01, y0, 0, 0, 0);   \
        y1 = __builtin_amdgcn_mfma_f32_16x16x32_bf16(b[bi][1], u11, y1, 0, 0, 0);
        if (role == 0) {
            Y4(0, d0v) res0 = y0; res1 = y1;                      // d1t (+d0)
            Y4(1, z)   tmp0 = y0; tmp1 = y1;                      // T1
            Y4(2, z)   tmp0 *= y0; tmp1 *= y1; res0 += tmp0; res1 += tmp1;
            Y4(3, z)   tmp0 = y0; tmp1 = y1;                      // T3
            Y4(4, z)   tmp0 *= y0; tmp1 *= y1;
            Y4(5, z)   tmp0 *= y0; tmp1 *= y1;
            Y4(6, z)   tmp0 *= y0; tmp1 *= y1; res0 += tmp0; res1 += tmp1;
        } else {
            Y4(0, z)   tmp0 = y0; tmp1 = y1;                      // T2
            Y4(1, z)   tmp0 *= y0; tmp1 *= y1;
            Y4(2, z)   tmp0 *= y0; tmp1 *= y1; res0 = tmp0; res1 = tmp1;
            Y4(3, z)   tmp0 = y0; tmp1 = y1;                      // T4
            Y4(4, z)   tmp0 *= y0; tmp1 *= y1;
            Y4(5, z)   tmp0 *= y0; tmp1 *= y1;
            Y4(6, z)   tmp0 *= y0; tmp1 *= y1;
            Y4(7, z)   tmp0 *= y0; tmp1 *= y1; res0 += tmp0; res1 += tmp1;
        }
#undef Y4
        __builtin_amdgcn_s_setprio(0);

        // ---- partials -> LDS -----------------------------------------------
        float* sb = &sbuf[t & 1][role][0];
        const int colw = strip * 16 + g * 4;
        *(f32x4*)&sb[l15 * LDSW + colw]        = res0;
        *(f32x4*)&sb[(16 + l15) * LDSW + colw] = res1;
        // lgkm-only barrier: VMEM stays in flight (proven R11/R14/R16/R19).
        asm volatile("s_waitcnt lgkmcnt(0)\n\ts_barrier" ::: "memory");

        // ---- store: A+B, nontemporal full 128-B lines ----------------------
        const float* pA = &sbuf[t & 1][0][0];
        const float* pB = &sbuf[t & 1][1][0];
        const int rr = threadIdx.x >> 3;          // 0..31
        const int c4 = (threadIdx.x & 7) * 4;     // 0..28
        f32x4 v = *(const f32x4*)&pA[rr * LDSW + c4];
        v = v + *(const f32x4*)&pB[rr * LDSW + c4];
        float* op = out + (row0 + (size_t)t * 32 + rr) * OUTF + cg * 32 + c4;
        __builtin_nontemporal_store(v, (f32x4*)op);
    }
}

extern "C" void kernel_launch(void* const* d_in, const int* in_sizes, int n_in,
                              void* d_out, int out_size, void* d_ws, size_t ws_size,
                              hipStream_t stream) {
    const float* x    = (const float*)d_in[0];
    const float* d0   = (const float*)d_in[1];
    const float* d1t  = (const float*)d_in[2];
    const float* d1w  = (const float*)d_in[3];
    const float* dnw1 = (const float*)d_in[4];
    const float* dnw2 = (const float*)d_in[5];
    unsigned short* wcs = (unsigned short*)d_ws;   // 480 KiB swizzled weights
    float* out = (float*)d_out;

    build_weights<<<(NMAT * OUTF * INF / 8 + 255) / 256, 256, 0, stream>>>(
        d1t, d1w, dnw1, dnw2, wcs);
    taylor_kernel<<<8 * (BATCH / RPB), 256, 0, stream>>>(x, d0, wcs, out);
}

// Round 22
// 41.252 us; speedup vs baseline: 1.8727x; 1.8727x over previous
//
#include <hip/hip_runtime.h>
#include <hip/hip_bf16.h>

#define BATCH 65536
#define INF   64
#define OUTF  256
#define NMAT  15
#define RPB   256          // rows per block
#define LDSW  68           // 64 cols + 4 pad floats

typedef __bf16 bf16x8 __attribute__((ext_vector_type(8)));
typedef float  f32x4  __attribute__((ext_vector_type(4)));

__device__ __forceinline__ unsigned short f2bf(float f) {
    unsigned int u = __float_as_uint(f);
    unsigned int r = (u + 0x7FFFu + ((u >> 16) & 1u)) >> 16;
    return (unsigned short)r;
}

// Opaque weight load: asm-produced value cannot be rematerialized/sunk by the
// compiler (guarantees register residency; R21 confirmed via FETCH drop).
__device__ __forceinline__ void wload(bf16x8& d, const void* p) {
    asm volatile("global_load_dwordx4 %0, %1, off" : "=v"(d) : "v"(p));
}

// ---------------------------------------------------------------------------
// Layouts (proven):
//   xs:  per 16-row group grp: byte = grp*2048 + s*1024 + lane*16
//        (lane = g*16 + r, r = row&15, k = s*32 + g*8 + j)
//   wcs: per (mat w, 16-col strip cs): byte = ((w*16+cs)*2+s)*1024 + lane*16
// ---------------------------------------------------------------------------
__global__ void prep(const float* __restrict__ x,
                     const float* __restrict__ d1t_w,
                     const float* __restrict__ d1_w,
                     const float* __restrict__ dn_w1,
                     const float* __restrict__ dn_w2,
                     unsigned short* __restrict__ wcs,
                     unsigned short* __restrict__ xs) {
    const int idx = blockIdx.x * 256 + threadIdx.x;   // one 16-B chunk each

    {   // x: chunk idx covers row = idx>>3, elems cc*8..cc*8+7
        const int row = idx >> 3, cc = idx & 7;
        const int s = cc >> 2, g = cc & 3;
        const int grp = row >> 4, r = row & 15;
        const float* xp = x + (size_t)row * INF + cc * 8;
        f32x4 v0 = *(const f32x4*)xp;
        f32x4 v1 = *(const f32x4*)(xp + 4);
        bf16x8 fr;
#pragma unroll
        for (int j = 0; j < 4; ++j) { fr[j] = (__bf16)v0[j]; fr[4 + j] = (__bf16)v1[j]; }
        *(bf16x8*)((char*)xs + (size_t)grp * 2048 + s * 1024 + g * 256 + r * 16) = fr;
    }

    if (idx < NMAT * OUTF * INF / 8) {
        const signed char kind[NMAT] = {0,1,2,1,2,2,1,2,2,2,1,2,2,2,2};
        const signed char sidx[NMAT] = {0,0,0,1,1,2,2,3,4,5,3,6,7,8,9};
        const int slot = idx >> 11, rem8 = idx & 2047;
        const int o = rem8 >> 3, cc = rem8 & 7;
        const int s = cc >> 2, g = cc & 3;
        const int i0 = cc * 8;
        const int cs = o >> 4, l = o & 15;
        const int k = kind[slot], si = sidx[slot];
        unsigned short o8[8];
#pragma unroll
        for (int j = 0; j < 8; ++j) {
            const int e = o * INF + i0 + j;
            float v;
            if (k == 0)      v = d1t_w[e];
            else if (k == 1) v = d1_w[si * OUTF * INF + e];
            else             v = dn_w2[si * OUTF * INF + e] * dn_w1[si * INF + i0 + j];
            o8[j] = f2bf(v);
        }
        char* dst = (char*)wcs + (((size_t)slot * 16 + cs) * 2 + s) * 1024 + g * 256 + l * 16;
        *(bf16x8*)dst = *(bf16x8*)o8;
    }
}

// 64-col blocks (R13 geometry, residency protected by asm wload): 512 thr =
// 4 strips x {A,B} roles; xs L2 re-reads halve (4 readers/row-chunk vs 8);
// stores are 256-B row segments. Per-wave register budget identical to R20.
__global__ __launch_bounds__(512, 4) void taylor_kernel(
    const unsigned short* __restrict__ xs, const float* __restrict__ d0w,
    const unsigned short* __restrict__ wcs, float* __restrict__ out)
{
    __shared__ float sbuf[2][2][32 * LDSW];   // 34.8 KB

    const int lane  = threadIdx.x & 63;
    const int wv    = threadIdx.x >> 6;   // 0..7
    const int strip = wv >> 1;            // 0..3
    const int role  = wv & 1;             // 0=A, 1=B
    const int l15   = lane & 15;
    const int g     = lane >> 4;
    // sharers of one row-chunk: bids {rc + 256k, k=0..3} -> all == rc mod 8
    const int cg    = blockIdx.x >> 8;    // 64-col group (0..3)
    const int rc    = blockIdx.x & 255;   // row-chunk (256 rows)
    const int cs    = cg * 4 + strip;     // global 16-col strip id (0..15)

    // ---- weight prologue: opaque asm loads (residency-guaranteed) ----------
    const int MA[8] = {0, 1, 2, 6, 7, 8, 9, 9};       // A uses first 7
    const int MB[8] = {3, 4, 5, 10, 11, 12, 13, 14};  // B uses all 8
    bf16x8 b[8][2];
    const char* wb0 = (const char*)wcs + lane * 16;
#pragma unroll
    for (int i = 0; i < 8; ++i) {
        const int m = role ? MB[i] : MA[i];
        if (role == 0 && i == 7) continue;            // A: only 7 mats
        const char* wp = wb0 + (((size_t)m * 16 + cs) * 2) * 1024;
        wload(b[i][0], wp);
        wload(b[i][1], wp + 1024);
    }
    asm volatile("s_waitcnt vmcnt(0)" ::: "memory");
    __builtin_amdgcn_sched_barrier(0);

    const f32x4 d0v = *(const f32x4*)(d0w + cs * 16 + g * 4);

    const size_t row0 = (size_t)rc * RPB;
    const char* xbase = (const char*)xs + (row0 >> 4) * 2048 + lane * 16;

    // prologue: tile 0
    bf16x8 u00 = *(const bf16x8*)(xbase);
    bf16x8 u01 = *(const bf16x8*)(xbase + 1024);
    bf16x8 u10 = *(const bf16x8*)(xbase + 2048);
    bf16x8 u11 = *(const bf16x8*)(xbase + 3072);

#pragma unroll
    for (int t = 0; t < 8; ++t) {
        f32x4 res0, res1, tmp0, tmp1, y0, y1;
        const f32x4 z = {0.f, 0.f, 0.f, 0.f};
        __builtin_amdgcn_s_setprio(1);
#define Y4(bi, c0)                                                                  \
        y0 = __builtin_amdgcn_mfma_f32_16x16x32_bf16(b[bi][0], u00, c0, 0, 0, 0);   \
        y1 = __builtin_amdgcn_mfma_f32_16x16x32_bf16(b[bi][0], u10, c0, 0, 0, 0);   \
        y0 = __builtin_amdgcn_mfma_f32_16x16x32_bf16(b[bi][1], u01, y0, 0, 0, 0);   \
        y1 = __builtin_amdgcn_mfma_f32_16x16x32_bf16(b[bi][1], u11, y1, 0, 0, 0);
        if (role == 0) {
            Y4(0, d0v) res0 = y0; res1 = y1;                      // d1t (+d0)
            Y4(1, z)   tmp0 = y0; tmp1 = y1;                      // T1
            Y4(2, z)   tmp0 *= y0; tmp1 *= y1; res0 += tmp0; res1 += tmp1;
            Y4(3, z)   tmp0 = y0; tmp1 = y1;                      // T3
            Y4(4, z)   tmp0 *= y0; tmp1 *= y1;
            Y4(5, z)   tmp0 *= y0; tmp1 *= y1;
            Y4(6, z)   tmp0 *= y0; tmp1 *= y1; res0 += tmp0; res1 += tmp1;
        } else {
            Y4(0, z)   tmp0 = y0; tmp1 = y1;                      // T2
            Y4(1, z)   tmp0 *= y0; tmp1 *= y1;
            Y4(2, z)   tmp0 *= y0; tmp1 *= y1; res0 = tmp0; res1 = tmp1;
            Y4(3, z)   tmp0 = y0; tmp1 = y1;                      // T4
            Y4(4, z)   tmp0 *= y0; tmp1 *= y1;
            Y4(5, z)   tmp0 *= y0; tmp1 *= y1;
            Y4(6, z)   tmp0 *= y0; tmp1 *= y1;
            Y4(7, z)   tmp0 *= y0; tmp1 *= y1; res0 += tmp0; res1 += tmp1;
        }
#undef Y4
        __builtin_amdgcn_s_setprio(0);

        // ---- pipelined load of tile t+1 into the same regs (WAR-ordered) ---
        if (t < 7) {
            const char* p = xbase + (size_t)(t + 1) * 4096;
            u00 = *(const bf16x8*)(p);
            u01 = *(const bf16x8*)(p + 1024);
            u10 = *(const bf16x8*)(p + 2048);
            u11 = *(const bf16x8*)(p + 3072);
        }

        // ---- partials -> LDS (strips write disjoint 16-col ranges) ---------
        float* sb = &sbuf[t & 1][role][0];
        const int colw = strip * 16 + g * 4;
        *(f32x4*)&sb[l15 * LDSW + colw]        = res0;
        *(f32x4*)&sb[(16 + l15) * LDSW + colw] = res1;
        // lgkm-only barrier: VMEM stays in flight (proven R11/R14/R16/R19).
        asm volatile("s_waitcnt lgkmcnt(0)\n\ts_barrier" ::: "memory");

        // ---- store: A+B, nontemporal 256-B row segments (2 full lines) -----
        const float* pA = &sbuf[t & 1][0][0];
        const float* pB = &sbuf[t & 1][1][0];
        const int rr = threadIdx.x >> 4;          // 0..31
        const int c4 = (threadIdx.x & 15) * 4;    // 0..60
        f32x4 v = *(const f32x4*)&pA[rr * LDSW + c4];
        v = v + *(const f32x4*)&pB[rr * LDSW + c4];
        float* op = out + (row0 + (size_t)t * 32 + rr) * OUTF + cg * 64 + c4;
        __builtin_nontemporal_store(v, (f32x4*)op);
    }
}

extern "C" void kernel_launch(void* const* d_in, const int* in_sizes, int n_in,
                              void* d_out, int out_size, void* d_ws, size_t ws_size,
                              hipStream_t stream) {
    const float* x    = (const float*)d_in[0];
    const float* d0   = (const float*)d_in[1];
    const float* d1t  = (const float*)d_in[2];
    const float* d1w  = (const float*)d_in[3];
    const float* dnw1 = (const float*)d_in[4];
    const float* dnw2 = (const float*)d_in[5];
    unsigned short* wcs = (unsigned short*)d_ws;                // 480 KiB
    float* out = (float*)d_out;

    unsigned short* xsb = (unsigned short*)((char*)d_ws + 512 * 1024);  // 8 MiB
    prep<<<BATCH * INF / 8 / 256, 256, 0, stream>>>(x, d1t, d1w, dnw1, dnw2, wcs, xsb);
    taylor_kernel<<<4 * (BATCH / RPB), 512, 0, stream>>>(xsb, d0, wcs, out);
}

// Round 23
// 40.818 us; speedup vs baseline: 1.8926x; 1.0106x over previous
//
#include <hip/hip_runtime.h>
#include <hip/hip_bf16.h>

#define BATCH 65536
#define INF   64
#define OUTF  256
#define NMAT  15
#define RPB   256          // rows per block
#define LDSW  68           // 64 cols + 4 pad floats

typedef __bf16 bf16x8 __attribute__((ext_vector_type(8)));
typedef float  f32x4  __attribute__((ext_vector_type(4)));

__device__ __forceinline__ unsigned short f2bf(float f) {
    unsigned int u = __float_as_uint(f);
    unsigned int r = (u + 0x7FFFu + ((u >> 16) & 1u)) >> 16;
    return (unsigned short)r;
}

// Opaque weight load: asm-produced value cannot be rematerialized/sunk
// (residency guaranteed; mechanism verified R21 via FETCH drop).
__device__ __forceinline__ void wload(bf16x8& d, const void* p) {
    asm volatile("global_load_dwordx4 %0, %1, off" : "=v"(d) : "v"(p));
}

// ---------------------------------------------------------------------------
// Weight layout (swizzled): per (mat w, 16-col strip cs):
//   byte = ((w*16+cs)*2+s)*1024 + lane*16   (lane = g*16+l15; k = s*32+g*8+j)
// slot order: 0=d1t, 1=d1_0, 2=M0, 3=d1_1, 4=M1, 5=M2, 6=d1_2, 7=M3, 8=M4,
// 9=M5, 10=d1_3, 11=M6, 12=M7, 13=M8, 14=M9  (M_p = dn_w2[p]*dn_w1[p][None,:])
// ---------------------------------------------------------------------------
__global__ void build_weights(const float* __restrict__ d1t_w,
                              const float* __restrict__ d1_w,
                              const float* __restrict__ dn_w1,
                              const float* __restrict__ dn_w2,
                              unsigned short* __restrict__ wcs) {
    const int idx = blockIdx.x * 256 + threadIdx.x;   // one 16-B chunk
    if (idx >= NMAT * OUTF * INF / 8) return;
    const signed char kind[NMAT] = {0,1,2,1,2,2,1,2,2,2,1,2,2,2,2};
    const signed char sidx[NMAT] = {0,0,0,1,1,2,2,3,4,5,3,6,7,8,9};
    const int slot = idx >> 11, rem8 = idx & 2047;
    const int o = rem8 >> 3, cc = rem8 & 7;
    const int s = cc >> 2, g = cc & 3;
    const int i0 = cc * 8;
    const int cs = o >> 4, l = o & 15;
    const int k = kind[slot], si = sidx[slot];
    unsigned short o8[8];
#pragma unroll
    for (int j = 0; j < 8; ++j) {
        const int e = o * INF + i0 + j;
        float v;
        if (k == 0)      v = d1t_w[e];
        else if (k == 1) v = d1_w[si * OUTF * INF + e];
        else             v = dn_w2[si * OUTF * INF + e] * dn_w1[si * INF + i0 + j];
        o8[j] = f2bf(v);
    }
    char* dst = (char*)wcs + (((size_t)slot * 16 + cs) * 2 + s) * 1024 + g * 256 + l * 16;
    *(bf16x8*)dst = *(bf16x8*)o8;
}

// R22 structure with IN-KERNEL x staging: coalesced row-major fp32 loads ->
// in-register bf16 cvt -> XOR-swizzled LDS fragment layout. Removes the prep
// launch and all xs HBM traffic (~5-6 us of the 41.3 total). Tile loop reads
// frags from LDS (lgkm, low latency).
// xsh layout: byte = grp*2048 + s*1024 + g*256 + (r ^ ((s*4+g)&7))*16
//   (grp = row>>4, r = row&15; XOR spreads the 8 (s,g) combos of one row
//    across banks on the staging write; read applies the same XOR.)
__global__ __launch_bounds__(512, 4) void taylor_kernel(
    const float* __restrict__ x, const float* __restrict__ d0w,
    const unsigned short* __restrict__ wcs, float* __restrict__ out)
{
    __shared__ char  xsh[32768];              // 256 rows x 64 k, bf16 swizzled
    __shared__ float sbuf[2][2][32 * LDSW];   // 34.8 KB combine buffer

    const int lane  = threadIdx.x & 63;
    const int wv    = threadIdx.x >> 6;   // 0..7
    const int strip = wv >> 1;            // 0..3
    const int role  = wv & 1;             // 0=A, 1=B
    const int l15   = lane & 15;
    const int g     = lane >> 4;
    // sharers of one row-chunk: bids {rc + 256k, k=0..3} -> all == rc mod 8
    const int cg    = blockIdx.x >> 8;    // 64-col group (0..3)
    const int rc    = blockIdx.x & 255;   // row-chunk (256 rows)
    const int cs    = cg * 4 + strip;     // global 16-col strip id (0..15)

    // ---- weight prologue: opaque asm loads (residency-guaranteed) ----------
    const int MA[8] = {0, 1, 2, 6, 7, 8, 9, 9};       // A uses first 7
    const int MB[8] = {3, 4, 5, 10, 11, 12, 13, 14};  // B uses all 8
    bf16x8 b[8][2];
    const char* wb0 = (const char*)wcs + lane * 16;
#pragma unroll
    for (int i = 0; i < 8; ++i) {
        const int m = role ? MB[i] : MA[i];
        if (role == 0 && i == 7) continue;            // A: only 7 mats
        const char* wp = wb0 + (((size_t)m * 16 + cs) * 2) * 1024;
        wload(b[i][0], wp);
        wload(b[i][1], wp + 1024);
    }

    const size_t row0 = (size_t)rc * RPB;

    // ---- in-kernel x staging: coalesced fp32 -> bf16 -> swizzled LDS -------
    {
        const float* xsrc = x + row0 * INF;
#pragma unroll
        for (int j = 0; j < 4; ++j) {
            const int c = j * 512 + (int)threadIdx.x;   // 8-float chunk 0..2047
            f32x4 v0 = *(const f32x4*)(xsrc + (size_t)c * 8);
            f32x4 v1 = *(const f32x4*)(xsrc + (size_t)c * 8 + 4);
            bf16x8 fr;
#pragma unroll
            for (int q = 0; q < 4; ++q) { fr[q] = (__bf16)v0[q]; fr[4 + q] = (__bf16)v1[q]; }
            const int row = c >> 3, cc = c & 7;
            const int ss = cc >> 2, gg = cc & 3;
            const int grp = row >> 4, r_ = row & 15;
            const int rx = r_ ^ ((ss * 4 + gg) & 7);
            *(bf16x8*)(xsh + grp * 2048 + ss * 1024 + gg * 256 + rx * 16) = fr;
        }
    }

    // drain weight wloads (rule #18: keep MFMAs below), then full barrier so
    // every wave sees the staged xsh.
    asm volatile("s_waitcnt vmcnt(0)" ::: "memory");
    __builtin_amdgcn_sched_barrier(0);
    __syncthreads();

    const f32x4 d0v = *(const f32x4*)(d0w + cs * 16 + g * 4);
    const int x0off = (l15 ^ g) * 16;             // s=0: (0*4+g)&7 = g
    const int x1off = (l15 ^ (4 + g)) * 16;       // s=1: (4+g)&7 = 4+g

#pragma unroll
    for (int t = 0; t < 8; ++t) {
        // ---- x frags from LDS (XOR-matched addresses) ----------------------
        const char* pg0 = xsh + (t * 2) * 2048 + g * 256;
        const char* pg1 = pg0 + 2048;
        bf16x8 u00 = *(const bf16x8*)(pg0 + x0off);
        bf16x8 u01 = *(const bf16x8*)(pg0 + 1024 + x1off);
        bf16x8 u10 = *(const bf16x8*)(pg1 + x0off);
        bf16x8 u11 = *(const bf16x8*)(pg1 + 1024 + x1off);

        f32x4 res0, res1, tmp0, tmp1, y0, y1;
        const f32x4 z = {0.f, 0.f, 0.f, 0.f};
        __builtin_amdgcn_s_setprio(1);
#define Y4(bi, c0)                                                                  \
        y0 = __builtin_amdgcn_mfma_f32_16x16x32_bf16(b[bi][0], u00, c0, 0, 0, 0);   \
        y1 = __builtin_amdgcn_mfma_f32_16x16x32_bf16(b[bi][0], u10, c0, 0, 0, 0);   \
        y0 = __builtin_amdgcn_mfma_f32_16x16x32_bf16(b[bi][1], u01, y0, 0, 0, 0);   \
        y1 = __builtin_amdgcn_mfma_f32_16x16x32_bf16(b[bi][1], u11, y1, 0, 0, 0);
        if (role == 0) {
            Y4(0, d0v) res0 = y0; res1 = y1;                      // d1t (+d0)
            Y4(1, z)   tmp0 = y0; tmp1 = y1;                      // T1
            Y4(2, z)   tmp0 *= y0; tmp1 *= y1; res0 += tmp0; res1 += tmp1;
            Y4(3, z)   tmp0 = y0; tmp1 = y1;                      // T3
            Y4(4, z)   tmp0 *= y0; tmp1 *= y1;
            Y4(5, z)   tmp0 *= y0; tmp1 *= y1;
            Y4(6, z)   tmp0 *= y0; tmp1 *= y1; res0 += tmp0; res1 += tmp1;
        } else {
            Y4(0, z)   tmp0 = y0; tmp1 = y1;                      // T2
            Y4(1, z)   tmp0 *= y0; tmp1 *= y1;
            Y4(2, z)   tmp0 *= y0; tmp1 *= y1; res0 = tmp0; res1 = tmp1;
            Y4(3, z)   tmp0 = y0; tmp1 = y1;                      // T4
            Y4(4, z)   tmp0 *= y0; tmp1 *= y1;
            Y4(5, z)   tmp0 *= y0; tmp1 *= y1;
            Y4(6, z)   tmp0 *= y0; tmp1 *= y1;
            Y4(7, z)   tmp0 *= y0; tmp1 *= y1; res0 += tmp0; res1 += tmp1;
        }
#undef Y4
        __builtin_amdgcn_s_setprio(0);

        // ---- partials -> LDS (strips write disjoint 16-col ranges) ---------
        float* sb = &sbuf[t & 1][role][0];
        const int colw = strip * 16 + g * 4;
        *(f32x4*)&sb[l15 * LDSW + colw]        = res0;
        *(f32x4*)&sb[(16 + l15) * LDSW + colw] = res1;
        // lgkm-only barrier: output stores stay in flight (proven R11/R14+).
        asm volatile("s_waitcnt lgkmcnt(0)\n\ts_barrier" ::: "memory");

        // ---- store: A+B, nontemporal 256-B row segments --------------------
        const float* pA = &sbuf[t & 1][0][0];
        const float* pB = &sbuf[t & 1][1][0];
        const int rr = threadIdx.x >> 4;          // 0..31
        const int c4 = (threadIdx.x & 15) * 4;    // 0..60
        f32x4 v = *(const f32x4*)&pA[rr * LDSW + c4];
        v = v + *(const f32x4*)&pB[rr * LDSW + c4];
        float* op = out + (row0 + (size_t)t * 32 + rr) * OUTF + cg * 64 + c4;
        __builtin_nontemporal_store(v, (f32x4*)op);
    }
}

extern "C" void kernel_launch(void* const* d_in, const int* in_sizes, int n_in,
                              void* d_out, int out_size, void* d_ws, size_t ws_size,
                              hipStream_t stream) {
    const float* x    = (const float*)d_in[0];
    const float* d0   = (const float*)d_in[1];
    const float* d1t  = (const float*)d_in[2];
    const float* d1w  = (const float*)d_in[3];
    const float* dnw1 = (const float*)d_in[4];
    const float* dnw2 = (const float*)d_in[5];
    unsigned short* wcs = (unsigned short*)d_ws;   // 480 KiB swizzled weights
    float* out = (float*)d_out;

    build_weights<<<(NMAT * OUTF * INF / 8 + 255) / 256, 256, 0, stream>>>(
        d1t, d1w, dnw1, dnw2, wcs);
    taylor_kernel<<<4 * (BATCH / RPB), 512, 0, stream>>>(x, d0, wcs, out);
}